// Round 14
// baseline (73.554 us; speedup 1.0000x reference)
//
#include <hip/hip_runtime.h>
#include <hip/hip_bf16.h>
#include <stdint.h>

#define NPG 28
#define KDIM 896
#define NOUT 256
#define BM 256
#define BK 32
#define KT (KDIM / BK)   // 28

typedef __attribute__((ext_vector_type(8))) __bf16 bf16x8;
typedef __attribute__((ext_vector_type(8))) ushort us8;
typedef __attribute__((ext_vector_type(4))) float f32x4;

__device__ __forceinline__ ushort f2bf(float v) {
    uint u = __float_as_uint(v);
    return (ushort)((u + 0x7fffu + ((u >> 16) & 1u)) >> 16);
}

__device__ __forceinline__ void gload_lds16(const void* g, void* l) {
    __builtin_amdgcn_global_load_lds(
        (const __attribute__((address_space(1))) void*)(uintptr_t)g,
        (__attribute__((address_space(3))) void*)(uintptr_t)l,
        16, 0, 0);
}

// ---------------- k_prep: fc1_w -> phase-tiled bf16 Wt [kt][256][32] ----------------
__global__ __launch_bounds__(256) void k_prep(const float* __restrict__ f1w,
                                              ushort* __restrict__ wt)
{
    __shared__ float t[32][33];
    const int tid = threadIdx.x;
    int b = blockIdx.x;
    int n0 = (b & 7) * 32, k0 = (b >> 3) * 32;
    int tx = tid & 31, ty = tid >> 5;
#pragma unroll
    for (int q = 0; q < 4; ++q)
        t[ty + q * 8][tx] = f1w[(k0 + ty + q * 8) * NOUT + n0 + tx];
    __syncthreads();
#pragma unroll
    for (int q = 0; q < 4; ++q)
        wt[(long)(k0 >> 5) * (NOUT * BK) + (n0 + ty + q * 8) * BK + tx] =
            f2bf(t[tx][ty + q * 8]);
}

// ---------------- k_fused helpers (BM=256, 16 waves 4Mx4N, wave-tile 64x64) ----------------
// Bs stage: 1 gload_lds per thread (1024 thr x 16B = 16KB tile), contiguous spans.
// Source granule pre-swizzled (phys = logical ^ ((row>>1)&3)); LDS dest linear.
__device__ __forceinline__ void stage_b1(const char* WtB, ushort* BsX, int kt, int tid) {
    const int o = (tid & 3) ^ ((tid >> 3) & 3);
    gload_lds16(WtB + (long)kt * 16384 + (tid >> 2) * 64 + o * 16,
                (char*)BsX + tid * 16);
}

// distributed A-gen: wave w -> octet w&3 (SGPR weights), row (w>>2)*64 + l.
__device__ __forceinline__ void agen_write(ushort* AsX, float2 av, int awoff,
                                           const float* w0, const float* w1, const float* bb) {
    union { us8 v; uint u[4]; } pk;
#pragma unroll
    for (int k = 0; k < 4; ++k) {
        float e0 = fmaxf(av.x * w0[2 * k]     + av.y * w1[2 * k]     + bb[2 * k],     0.f);
        float e1 = fmaxf(av.x * w0[2 * k + 1] + av.y * w1[2 * k + 1] + bb[2 * k + 1], 0.f);
        __hip_bfloat162 h = __float22bfloat162_rn(make_float2(e0, e1));
        pk.u[k] = *reinterpret_cast<uint*>(&h);
    }
    *(us8*)&AsX[awoff] = pk.v;
}

// one K-step MFMA cluster per wave: 4x4 = 16 MFMAs; af per-mi (round-13 reg-lean form)
__device__ __forceinline__ void compute_mfma(const ushort* AsX, const ushort* BsX,
                                             f32x4 acc[4][4], int a_off, int b_off) {
    bf16x8 bfr[4];
#pragma unroll
    for (int ni = 0; ni < 4; ++ni)
        bfr[ni] = *(const bf16x8*)(&BsX[b_off + ni * 512]);
    __builtin_amdgcn_s_setprio(1);
#pragma unroll
    for (int mi = 0; mi < 4; ++mi) {
        bf16x8 af = *(const bf16x8*)(&AsX[a_off + mi * 512]);
#pragma unroll
        for (int ni = 0; ni < 4; ++ni)
            acc[mi][ni] = __builtin_amdgcn_mfma_f32_16x16x32_bf16(
                af, bfr[ni], acc[mi][ni], 0, 0, 0);
    }
    __builtin_amdgcn_s_setprio(0);
}

// ---------------- k_fused: in-block aggregation + triple-Bs counted GEMM pipeline ----------------
// 256 blocks x 1024 threads, BM=256, LDS 136KB (1 block/CU, 16 waves).
// Agg panel LDS-resident -> loop VMEM = exactly 1 gload_lds/thread/phase -> vmcnt(1) counted.
__global__ __launch_bounds__(1024, 4) void k_fused(
    const float* __restrict__ x, const int* __restrict__ dst,
    const ushort* __restrict__ Wt,
    const float* __restrict__ cw, const float* __restrict__ cb,
    const float* __restrict__ f1b, const float* __restrict__ f2w,
    const float* __restrict__ f2b, float* __restrict__ out, int Bsz)
{
    __shared__ ushort As0[BM * BK], As1[BM * BK];                     // 2 x 16KB
    __shared__ ushort Bs0[NOUT * BK], Bs1[NOUT * BK], Bs2[NOUT * BK]; // 3 x 16KB
    __shared__ float2 Agg[NPG][BM];                                   // 56KB -> 136KB total

    const int tid = threadIdx.x;
    const int w = tid >> 6, l = tid & 63;
    const int wM = w >> 2, wN = w & 3;
    const int l15 = l & 15, lhi = (l >> 4) & 3;
    const long m0 = (long)blockIdx.x * BM;
    const char* WtB = (const char*)Wt;

    // ---- issue first two B-tile stages NOW; latency hides under aggregation ----
    stage_b1(WtB, Bs0, 0, tid);
    stage_b1(WtB, Bs1, 1, tid);

    // ---- in-block aggregation: 32 groups x 8 graphs, 2-deep load pipeline ----
    {
        int*   pks = (int*)As0;    // [32][32] scratch (As dead until GEMM)
        float* sxp = (float*)As1;  // [32][32][2] scratch
        const int g5 = tid >> 5;
        const int j  = tid & 31;

        int4 d4 = make_int4(0, 0, 0, 0);
        float2 xx = make_float2(0.f, 0.f);
        {
            long gb = (m0 + (long)g5 * 8) * NPG;
            if (j < NPG) {
                d4 = ((const int4*)dst)[gb + j];
                xx = ((const float2*)x)[gb + j];
            }
        }
        for (int it = 0; it < 8; ++it) {
            const int gr = g5 * 8 + it;
            const long gb = (m0 + gr) * NPG;
            int4 d4n = make_int4(0, 0, 0, 0);
            float2 xxn = make_float2(0.f, 0.f);
            if (it < 7 && j < NPG) {
                d4n = ((const int4*)dst)[gb + NPG + j];
                xxn = ((const float2*)x)[gb + NPG + j];
            }
            if (j < NPG) {
                int gbi = (int)gb;
                pks[g5 * 32 + j] = (d4.x - gbi) | ((d4.y - gbi) << 8) |
                                   ((d4.z - gbi) << 16) | ((d4.w - gbi) << 24);
            }
            asm volatile("s_waitcnt lgkmcnt(0)" ::: "memory");  // pk visible wave-wide

            const uint repj = (uint)j * 0x01010101u;
            uint cp0 = 0, cp1 = 0, cp2 = 0, cp3 = 0;
            int cnt = 0;
#pragma unroll
            for (int s4 = 0; s4 < 7; ++s4) {
                int4 pv = *(const int4*)&pks[g5 * 32 + s4 * 4];
#pragma unroll
                for (int r = 0; r < 4; ++r) {
                    uint v = ((const uint*)&pv)[r] ^ repj;
                    uint zb = ~(((v & 0x7F7F7F7Fu) + 0x7F7F7F7Fu) | v) & 0x80808080u;
                    uint c = (uint)__popc(zb);
                    cnt += (int)c;
                    int s = s4 * 4 + r;
                    uint nib = c << ((s & 7) * 4);
                    if (s < 8)       cp0 |= nib;
                    else if (s < 16) cp1 |= nib;
                    else if (s < 24) cp2 |= nib;
                    else             cp3 |= nib;
                }
            }

            const float dinv = rsqrtf((float)(1 + cnt));
            const float sx0 = xx.x * dinv, sx1 = xx.y * dinv;
            if (j < NPG) {
                sxp[(g5 * 32 + j) * 2]     = sx0;
                sxp[(g5 * 32 + j) * 2 + 1] = sx1;
            }
            asm volatile("s_waitcnt lgkmcnt(0)" ::: "memory");  // sx visible wave-wide

            float a0 = sx0, a1 = sx1;
#pragma unroll
            for (int s = 0; s < NPG; ++s) {
                float2 sv = *(const float2*)&sxp[(g5 * 32 + s) * 2];
                uint cpw = (s < 8) ? cp0 : (s < 16) ? cp1 : (s < 24) ? cp2 : cp3;
                float cf = (float)((cpw >> ((s & 7) * 4)) & 0xFu);
                a0 += cf * sv.x;
                a1 += cf * sv.y;
            }
            if (j < NPG)
                Agg[j][gr] = make_float2(a0 * dinv, a1 * dinv);
            d4 = d4n; xx = xxn;
        }
    }

    // ---- GEMM setup ----
    const int ao = __builtin_amdgcn_readfirstlane(w & 3);
    const int arow = (w >> 2) * 64 + l;                      // 0..255
    const int awoff = arow * 32 + ((ao ^ ((l >> 1) & 3)) * 8);
    float w0[8], w1[8], bb[8];
#pragma unroll
    for (int k = 0; k < 8; ++k) {
        w0[k] = cw[ao * 8 + k]; w1[k] = cw[32 + ao * 8 + k]; bb[k] = cb[ao * 8 + k];
    }
    const int swz = (lhi ^ ((l15 >> 1) & 3)) * 8;
    const int a_off = (wM * 64 + l15) * 32 + swz;            // + mi*512
    const int b_off = (wN * 64 + l15) * 32 + swz;            // + ni*512

    f32x4 acc[4][4];
#pragma unroll
    for (int mi = 0; mi < 4; ++mi)
#pragma unroll
        for (int ni = 0; ni < 4; ++ni) acc[mi][ni] = (f32x4){0.f, 0.f, 0.f, 0.f};

    // ---- publish Agg (+ Bs0/Bs1 already retired: agg's compiler waits drained older loads) ----
    __syncthreads();
    agen_write(As0, Agg[0][arow], awoff, w0, w1, bb);
    asm volatile("s_waitcnt lgkmcnt(0)" ::: "memory");
    __builtin_amdgcn_s_barrier();                            // As(0) published

    // phase: STAGE(kt+2) -> COMPUTE(kt) -> vmcnt(1) [stage(kt+1) landed] -> AGEN(kt+1) -> lgkm0 -> bar
#define PH(BC, BS, AC, AN, KS) do {                                            \
        stage_b1(WtB, BS, (KS), tid);                                          \
        compute_mfma(AC, BC, acc, a_off, b_off);                               \
        asm volatile("s_waitcnt vmcnt(1)" ::: "memory");                       \
        agen_write(AN, Agg[(KS) - 1][arow], awoff, w0, w1, bb);                \
        asm volatile("s_waitcnt lgkmcnt(0)" ::: "memory");                     \
        __builtin_amdgcn_s_barrier();                                          \
    } while (0)

    // main loop kt = 0..23 (6-phase blocks -> all buffer indices static)
    for (int kt = 0; kt < 24; kt += 6) {
        PH(Bs0, Bs2, As0, As1, kt + 2);
        PH(Bs1, Bs0, As1, As0, kt + 3);
        PH(Bs2, Bs1, As0, As1, kt + 4);
        PH(Bs0, Bs2, As1, As0, kt + 5);
        PH(Bs1, Bs0, As0, As1, kt + 6);
        PH(Bs2, Bs1, As1, As0, kt + 7);
    }
    // tail: phases 24,25 full; 26 no stage; 27 compute only
    PH(Bs0, Bs2, As0, As1, 26);   // compute 24, agen 25, stage 26
    PH(Bs1, Bs0, As1, As0, 27);   // compute 25, agen 26, stage 27
    {   // phase 26
        compute_mfma(As0, Bs2, acc, a_off, b_off);
        asm volatile("s_waitcnt vmcnt(0)" ::: "memory");   // drain stage(27)
        agen_write(As1, Agg[27][arow], awoff, w0, w1, bb);
        asm volatile("s_waitcnt lgkmcnt(0)" ::: "memory");
        __builtin_amdgcn_s_barrier();
    }
    {   // phase 27
        compute_mfma(As1, Bs0, acc, a_off, b_off);
        asm volatile("s_waitcnt lgkmcnt(0)" ::: "memory");
        __builtin_amdgcn_s_barrier();
    }
#undef PH

    // ---- fused epilogue: +bias, row L2-norm, FC2, sigmoid/softplus ----
    float b1[4], w20[4], w21[4];
#pragma unroll
    for (int ni = 0; ni < 4; ++ni) {
        int col = wN * 64 + ni * 16 + l15;
        b1[ni] = f1b[col];
        w20[ni] = f2w[col * 2 + 0];
        w21[ni] = f2w[col * 2 + 1];
    }
    float* red    = (float*)As0;     // 16KB scratch (all loop reads drained)
    float* red_ss = red;             // [256][4]
    float* red_p0 = red + 1024;
    float* red_p1 = red + 2048;
    float* red_rn = red + 3072;      // [256]

#pragma unroll
    for (int mi = 0; mi < 4; ++mi) {
        float ssr[4], p0r[4], p1r[4];
#pragma unroll
        for (int r = 0; r < 4; ++r) { ssr[r] = 0.f; p0r[r] = 0.f; p1r[r] = 0.f; }
#pragma unroll
        for (int ni = 0; ni < 4; ++ni) {
#pragma unroll
            for (int r = 0; r < 4; ++r) {
                float v = acc[mi][ni][r] + b1[ni];
                acc[mi][ni][r] = v;
                ssr[r] += v * v;
                p0r[r] += v * w20[ni];
                p1r[r] += v * w21[ni];
            }
        }
#pragma unroll
        for (int m = 1; m < 16; m <<= 1) {
#pragma unroll
            for (int r = 0; r < 4; ++r) {
                ssr[r] += __shfl_xor(ssr[r], m);
                p0r[r] += __shfl_xor(p0r[r], m);
                p1r[r] += __shfl_xor(p1r[r], m);
            }
        }
        if (l15 == 0) {
            int rowb = wM * 64 + mi * 16 + lhi * 4;
#pragma unroll
            for (int r = 0; r < 4; ++r) {
                red_ss[(rowb + r) * 4 + wN] = ssr[r];
                red_p0[(rowb + r) * 4 + wN] = p0r[r];
                red_p1[(rowb + r) * 4 + wN] = p1r[r];
            }
        }
    }
    __syncthreads();

    if (tid < BM) {
        int row = tid;
        float ss = red_ss[row * 4 + 0] + red_ss[row * 4 + 1] + red_ss[row * 4 + 2] + red_ss[row * 4 + 3];
        float p0 = red_p0[row * 4 + 0] + red_p0[row * 4 + 1] + red_p0[row * 4 + 2] + red_p0[row * 4 + 3];
        float p1 = red_p1[row * 4 + 0] + red_p1[row * 4 + 1] + red_p1[row * 4 + 2] + red_p1[row * 4 + 3];
        float rn = 1.0f / fmaxf(sqrtf(ss), 1e-12f);
        float x0 = p0 * rn + f2b[0];
        float x1 = p1 * rn + f2b[1];
        float mu = 1.0f / (1.0f + expf(-x0));
        float th = (x1 > 0.f) ? (x1 + log1pf(expf(-x1))) : log1pf(expf(x1));
        long gr = m0 + row;
        out[(long)Bsz * NOUT + gr] = mu;
        out[(long)Bsz * NOUT + Bsz + gr] = th;
        red_rn[row] = rn;
    }
    __syncthreads();

#pragma unroll
    for (int mi = 0; mi < 4; ++mi) {
        float rn[4];
#pragma unroll
        for (int r = 0; r < 4; ++r) rn[r] = red_rn[wM * 64 + mi * 16 + lhi * 4 + r];
#pragma unroll
        for (int ni = 0; ni < 4; ++ni) {
#pragma unroll
            for (int r = 0; r < 4; ++r) {
                long row = m0 + wM * 64 + mi * 16 + lhi * 4 + r;
                out[row * NOUT + wN * 64 + ni * 16 + l15] = acc[mi][ni][r] * rn[r];
            }
        }
    }
}

extern "C" void kernel_launch(void* const* d_in, const int* in_sizes, int n_in,
                              void* d_out, int out_size, void* d_ws, size_t ws_size,
                              hipStream_t stream) {
    const float* x   = (const float*)d_in[0];
    const int*   ei  = (const int*)d_in[1];
    const float* cw  = (const float*)d_in[2];
    const float* cb  = (const float*)d_in[3];
    const float* f1w = (const float*)d_in[4];
    const float* f1b = (const float*)d_in[5];
    const float* f2w = (const float*)d_in[6];
    const float* f2b = (const float*)d_in[7];
    float* out = (float*)d_out;

    const int Nn  = in_sizes[0] / 2;       // nodes
    const int Bsz = Nn / NPG;              // graphs
    const int E   = in_sizes[1] / 2;       // edges
    const int* dst = ei + E;

    ushort* Wt = (ushort*)d_ws;            // [28][256][32] bf16 (phase-tiled)

    const int nTr = (KDIM / 32) * (NOUT / 32);   // 224
    k_prep<<<nTr, 256, 0, stream>>>(f1w, Wt);
    k_fused<<<Bsz / BM, 1024, 0, stream>>>(x, dst, Wt, cw, cb, f1b, f2w, f2b, out, Bsz);
}

// Round 15
// 71.323 us; speedup vs baseline: 1.0313x; 1.0313x over previous
//
#include <hip/hip_runtime.h>
#include <hip/hip_bf16.h>
#include <stdint.h>

#define NPG 28
#define KDIM 896
#define NOUT 256
#define BM 128
#define BK 32
#define KT (KDIM / BK)   // 28

typedef __attribute__((ext_vector_type(8))) __bf16 bf16x8;
typedef __attribute__((ext_vector_type(8))) ushort us8;
typedef __attribute__((ext_vector_type(4))) float f32x4;

__device__ __forceinline__ ushort f2bf(float v) {
    uint u = __float_as_uint(v);
    return (ushort)((u + 0x7fffu + ((u >> 16) & 1u)) >> 16);
}

__device__ __forceinline__ void gload_lds16(const void* g, void* l) {
    __builtin_amdgcn_global_load_lds(
        (const __attribute__((address_space(1))) void*)(uintptr_t)g,
        (__attribute__((address_space(3))) void*)(uintptr_t)l,
        16, 0, 0);
}

// ---------------- k_prep: fc1_w -> phase-tiled bf16 Wt [kt][256][32] ----------------
__global__ __launch_bounds__(256) void k_prep(const float* __restrict__ f1w,
                                              ushort* __restrict__ wt)
{
    __shared__ float t[32][33];
    const int tid = threadIdx.x;
    int b = blockIdx.x;
    int n0 = (b & 7) * 32, k0 = (b >> 3) * 32;
    int tx = tid & 31, ty = tid >> 5;
#pragma unroll
    for (int q = 0; q < 4; ++q)
        t[ty + q * 8][tx] = f1w[(k0 + ty + q * 8) * NOUT + n0 + tx];
    __syncthreads();
#pragma unroll
    for (int q = 0; q < 4; ++q)
        wt[(long)(k0 >> 5) * (NOUT * BK) + (n0 + ty + q * 8) * BK + tx] =
            f2bf(t[tx][ty + q * 8]);
}

// ---------------- k_fused helpers (BM=128, 8 waves 2Mx4N, wave-tile 64x64) ----------------
// Bs stage: 2 gload_lds per thread (512 thr), 1KB-contiguous spans from phase-tiled Wt.
// Source granule pre-swizzled (phys = logical ^ ((row>>1)&3)); LDS dest linear.
__device__ __forceinline__ void stage_b2(const char* WtB, ushort* BsX, int kt, int tid) {
    const int o = (tid & 3) ^ ((tid >> 3) & 3);
    const long tb = (long)kt * 16384 + (tid >> 2) * 64 + o * 16;
    gload_lds16(WtB + tb,        (char*)BsX + tid * 16);
    gload_lds16(WtB + tb + 8192, (char*)BsX + 8192 + tid * 16);
}

// distributed A-gen: wave w -> octet w&3 (SGPR weights), row (w>>2)*64 + l.
__device__ __forceinline__ void agen_write(ushort* AsX, float2 av, int awoff,
                                           const float* w0, const float* w1, const float* bb) {
    union { us8 v; uint u[4]; } pk;
#pragma unroll
    for (int k = 0; k < 4; ++k) {
        float e0 = fmaxf(av.x * w0[2 * k]     + av.y * w1[2 * k]     + bb[2 * k],     0.f);
        float e1 = fmaxf(av.x * w0[2 * k + 1] + av.y * w1[2 * k + 1] + bb[2 * k + 1], 0.f);
        __hip_bfloat162 h = __float22bfloat162_rn(make_float2(e0, e1));
        pk.u[k] = *reinterpret_cast<uint*>(&h);
    }
    *(us8*)&AsX[awoff] = pk.v;
}

// one K-step MFMA cluster per wave: 4x4 = 16 MFMAs; af per-mi (reg-lean, round-13 form)
__device__ __forceinline__ void compute_mfma(const ushort* AsX, const ushort* BsX,
                                             f32x4 acc[4][4], int a_off, int b_off) {
    bf16x8 bfr[4];
#pragma unroll
    for (int ni = 0; ni < 4; ++ni)
        bfr[ni] = *(const bf16x8*)(&BsX[b_off + ni * 512]);
    __builtin_amdgcn_s_setprio(1);
#pragma unroll
    for (int mi = 0; mi < 4; ++mi) {
        bf16x8 af = *(const bf16x8*)(&AsX[a_off + mi * 512]);
#pragma unroll
        for (int ni = 0; ni < 4; ++ni)
            acc[mi][ni] = __builtin_amdgcn_mfma_f32_16x16x32_bf16(
                af, bfr[ni], acc[mi][ni], 0, 0, 0);
    }
    __builtin_amdgcn_s_setprio(0);
}

// ---------------- k_fused: in-block aggregation + dbuf GEMM, BM=128, 2 blocks/CU ----------------
// Round-14 fusion regressed via (a) Agg[28][256] 28-way write conflict (stride 512 words ≡ 0
// mod 32) and (b) 136KB LDS -> 1 block/CU lockstep. Fix: BM=128 geometry (78KB -> 2 blocks/CU,
// the ~12µs lever per rounds 9/11) + Agg[28][129] pad (stride 258 words ≡ 2 mod 32 -> 2-way).
__global__ __launch_bounds__(512, 4) void k_fused(
    const float* __restrict__ x, const int* __restrict__ dst,
    const ushort* __restrict__ Wt,
    const float* __restrict__ cw, const float* __restrict__ cb,
    const float* __restrict__ f1b, const float* __restrict__ f2w,
    const float* __restrict__ f2b, float* __restrict__ out, int Bsz)
{
    __shared__ ushort As0[BM * BK], As1[BM * BK];     // 2 x 8KB
    __shared__ ushort Bs0[NOUT * BK], Bs1[NOUT * BK]; // 2 x 16KB
    __shared__ float2 Agg[NPG][BM + 1];               // 28.9KB (pad -> conflict-free writes)

    const int tid = threadIdx.x;
    const int w = tid >> 6, l = tid & 63;
    const int wM = w >> 2, wN = w & 3;
    const int l15 = l & 15, lhi = (l >> 4) & 3;
    const long m0 = (long)blockIdx.x * BM;
    const char* WtB = (const char*)Wt;

    // ---- issue first B-tile stage NOW; latency hides under aggregation ----
    stage_b2(WtB, Bs0, 0, tid);

    // ---- in-block aggregation: 16 groups x 8 graphs, 2-deep load pipeline (round-14 verified) ----
    {
        int*   pks = (int*)As0;    // [16][32] scratch (As dead until GEMM)
        float* sxp = (float*)As1;  // [16][32][2] scratch
        const int g5 = tid >> 5;   // 0..15
        const int j  = tid & 31;

        int4 d4 = make_int4(0, 0, 0, 0);
        float2 xx = make_float2(0.f, 0.f);
        {
            long gb = (m0 + (long)g5 * 8) * NPG;
            if (j < NPG) {
                d4 = ((const int4*)dst)[gb + j];
                xx = ((const float2*)x)[gb + j];
            }
        }
        for (int it = 0; it < 8; ++it) {
            const int gr = g5 * 8 + it;                    // 0..127
            const long gb = (m0 + gr) * NPG;
            int4 d4n = make_int4(0, 0, 0, 0);
            float2 xxn = make_float2(0.f, 0.f);
            if (it < 7 && j < NPG) {
                d4n = ((const int4*)dst)[gb + NPG + j];
                xxn = ((const float2*)x)[gb + NPG + j];
            }
            if (j < NPG) {
                int gbi = (int)gb;
                pks[g5 * 32 + j] = (d4.x - gbi) | ((d4.y - gbi) << 8) |
                                   ((d4.z - gbi) << 16) | ((d4.w - gbi) << 24);
            }
            asm volatile("s_waitcnt lgkmcnt(0)" ::: "memory");  // pk visible wave-wide

            const uint repj = (uint)j * 0x01010101u;
            uint cp0 = 0, cp1 = 0, cp2 = 0, cp3 = 0;
            int cnt = 0;
#pragma unroll
            for (int s4 = 0; s4 < 7; ++s4) {
                int4 pv = *(const int4*)&pks[g5 * 32 + s4 * 4];
#pragma unroll
                for (int r = 0; r < 4; ++r) {
                    uint v = ((const uint*)&pv)[r] ^ repj;
                    uint zb = ~(((v & 0x7F7F7F7Fu) + 0x7F7F7F7Fu) | v) & 0x80808080u;
                    uint c = (uint)__popc(zb);
                    cnt += (int)c;
                    int s = s4 * 4 + r;
                    uint nib = c << ((s & 7) * 4);
                    if (s < 8)       cp0 |= nib;
                    else if (s < 16) cp1 |= nib;
                    else if (s < 24) cp2 |= nib;
                    else             cp3 |= nib;
                }
            }

            const float dinv = rsqrtf((float)(1 + cnt));
            const float sx0 = xx.x * dinv, sx1 = xx.y * dinv;
            if (j < NPG) {
                sxp[(g5 * 32 + j) * 2]     = sx0;
                sxp[(g5 * 32 + j) * 2 + 1] = sx1;
            }
            asm volatile("s_waitcnt lgkmcnt(0)" ::: "memory");  // sx visible wave-wide

            float a0 = sx0, a1 = sx1;
#pragma unroll
            for (int s = 0; s < NPG; ++s) {
                float2 sv = *(const float2*)&sxp[(g5 * 32 + s) * 2];
                uint cpw = (s < 8) ? cp0 : (s < 16) ? cp1 : (s < 24) ? cp2 : cp3;
                float cf = (float)((cpw >> ((s & 7) * 4)) & 0xFu);
                a0 += cf * sv.x;
                a1 += cf * sv.y;
            }
            if (j < NPG)
                Agg[j][gr] = make_float2(a0 * dinv, a1 * dinv);
            d4 = d4n; xx = xxn;
        }
    }

    // ---- GEMM setup ----
    const int ao = __builtin_amdgcn_readfirstlane(w & 3);
    const int arow = wM * 64 + l;                            // 0..127
    const int awoff = arow * 32 + ((ao ^ ((l >> 1) & 3)) * 8);
    float w0[8], w1[8], bb[8];
#pragma unroll
    for (int k = 0; k < 8; ++k) {
        w0[k] = cw[ao * 8 + k]; w1[k] = cw[32 + ao * 8 + k]; bb[k] = cb[ao * 8 + k];
    }
    const int swz = (lhi ^ ((l15 >> 1) & 3)) * 8;
    const int a_off = (wM * 64 + l15) * 32 + swz;            // + mi*512
    const int b_off = (wN * 64 + l15) * 32 + swz;            // + ni*512

    f32x4 acc[4][4];
#pragma unroll
    for (int mi = 0; mi < 4; ++mi)
#pragma unroll
        for (int ni = 0; ni < 4; ++ni) acc[mi][ni] = (f32x4){0.f, 0.f, 0.f, 0.f};

    // ---- publish Agg; drain stage(0); build As(0) ----
    __syncthreads();
    agen_write(As0, Agg[0][arow], awoff, w0, w1, bb);
    asm volatile("s_waitcnt lgkmcnt(0)" ::: "memory");
    __builtin_amdgcn_s_barrier();                            // As(0) + Bs(0) published

    // ---- main loop: round-9-proven full-drain dbuf discipline ----
    for (int kt = 0; kt < KT; kt += 2) {
        stage_b2(WtB, Bs1, kt + 1, tid);
        agen_write(As1, Agg[kt + 1][arow], awoff, w0, w1, bb);
        compute_mfma(As0, Bs0, acc, a_off, b_off);
        __syncthreads();

        if (kt + 2 < KT) {
            stage_b2(WtB, Bs0, kt + 2, tid);
            agen_write(As0, Agg[kt + 2][arow], awoff, w0, w1, bb);
        }
        compute_mfma(As1, Bs1, acc, a_off, b_off);
        __syncthreads();
    }

    // ---- fused epilogue: +bias, row L2-norm, FC2, sigmoid/softplus ----
    float b1[4], w20[4], w21[4];
#pragma unroll
    for (int ni = 0; ni < 4; ++ni) {
        int col = wN * 64 + ni * 16 + l15;
        b1[ni] = f1b[col];
        w20[ni] = f2w[col * 2 + 0];
        w21[ni] = f2w[col * 2 + 1];
    }
    float* red    = (float*)As0;     // 8KB scratch (all loop reads drained)
    float* red_ss = red;             // [128][4]
    float* red_p0 = red + 512;
    float* red_p1 = red + 1024;
    float* red_rn = red + 1536;      // [128]

#pragma unroll
    for (int mi = 0; mi < 4; ++mi) {
        float ssr[4], p0r[4], p1r[4];
#pragma unroll
        for (int r = 0; r < 4; ++r) { ssr[r] = 0.f; p0r[r] = 0.f; p1r[r] = 0.f; }
#pragma unroll
        for (int ni = 0; ni < 4; ++ni) {
#pragma unroll
            for (int r = 0; r < 4; ++r) {
                float v = acc[mi][ni][r] + b1[ni];
                acc[mi][ni][r] = v;
                ssr[r] += v * v;
                p0r[r] += v * w20[ni];
                p1r[r] += v * w21[ni];
            }
        }
#pragma unroll
        for (int m = 1; m < 16; m <<= 1) {
#pragma unroll
            for (int r = 0; r < 4; ++r) {
                ssr[r] += __shfl_xor(ssr[r], m);
                p0r[r] += __shfl_xor(p0r[r], m);
                p1r[r] += __shfl_xor(p1r[r], m);
            }
        }
        if (l15 == 0) {
            int rowb = wM * 64 + mi * 16 + lhi * 4;
#pragma unroll
            for (int r = 0; r < 4; ++r) {
                red_ss[(rowb + r) * 4 + wN] = ssr[r];
                red_p0[(rowb + r) * 4 + wN] = p0r[r];
                red_p1[(rowb + r) * 4 + wN] = p1r[r];
            }
        }
    }
    __syncthreads();

    if (tid < BM) {
        int row = tid;
        float ss = red_ss[row * 4 + 0] + red_ss[row * 4 + 1] + red_ss[row * 4 + 2] + red_ss[row * 4 + 3];
        float p0 = red_p0[row * 4 + 0] + red_p0[row * 4 + 1] + red_p0[row * 4 + 2] + red_p0[row * 4 + 3];
        float p1 = red_p1[row * 4 + 0] + red_p1[row * 4 + 1] + red_p1[row * 4 + 2] + red_p1[row * 4 + 3];
        float rn = 1.0f / fmaxf(sqrtf(ss), 1e-12f);
        float x0 = p0 * rn + f2b[0];
        float x1 = p1 * rn + f2b[1];
        float mu = 1.0f / (1.0f + expf(-x0));
        float th = (x1 > 0.f) ? (x1 + log1pf(expf(-x1))) : log1pf(expf(x1));
        long gr = m0 + row;
        out[(long)Bsz * NOUT + gr] = mu;
        out[(long)Bsz * NOUT + Bsz + gr] = th;
        red_rn[row] = rn;
    }
    __syncthreads();

#pragma unroll
    for (int mi = 0; mi < 4; ++mi) {
        float rn[4];
#pragma unroll
        for (int r = 0; r < 4; ++r) rn[r] = red_rn[wM * 64 + mi * 16 + lhi * 4 + r];
#pragma unroll
        for (int ni = 0; ni < 4; ++ni) {
#pragma unroll
            for (int r = 0; r < 4; ++r) {
                long row = m0 + wM * 64 + mi * 16 + lhi * 4 + r;
                out[row * NOUT + wN * 64 + ni * 16 + l15] = acc[mi][ni][r] * rn[r];
            }
        }
    }
}

extern "C" void kernel_launch(void* const* d_in, const int* in_sizes, int n_in,
                              void* d_out, int out_size, void* d_ws, size_t ws_size,
                              hipStream_t stream) {
    const float* x   = (const float*)d_in[0];
    const int*   ei  = (const int*)d_in[1];
    const float* cw  = (const float*)d_in[2];
    const float* cb  = (const float*)d_in[3];
    const float* f1w = (const float*)d_in[4];
    const float* f1b = (const float*)d_in[5];
    const float* f2w = (const float*)d_in[6];
    const float* f2b = (const float*)d_in[7];
    float* out = (float*)d_out;

    const int Nn  = in_sizes[0] / 2;       // nodes
    const int Bsz = Nn / NPG;              // graphs
    const int E   = in_sizes[1] / 2;       // edges
    const int* dst = ei + E;

    ushort* Wt = (ushort*)d_ws;            // [28][256][32] bf16 (phase-tiled)

    const int nTr = (KDIM / 32) * (NOUT / 32);   // 224
    k_prep<<<nTr, 256, 0, stream>>>(f1w, Wt);
    k_fused<<<Bsz / BM, 512, 0, stream>>>(x, dst, Wt, cw, cb, f1b, f2w, f2b, out, Bsz);
}